// Round 4
// baseline (37838.007 us; speedup 1.0000x reference)
//
#include <hip/hip_runtime.h>
#include <hip/hip_bf16.h>
#include <stdint.h>

// Problem dims
#define BB 64
#define TT 512
#define EE 512
#define HH 1024
#define KTOT 1536          // E + H
#define CHUNK 8            // h-columns per workgroup (128 WGs per direction)
#define KSLICE 384         // K per wave (KTOT / 4 waves)
#define NKI 12             // KSLICE / 32
#define NWGD 128           // workgroups per direction
#define NWG  256           // total workgroups

typedef __bf16 bf16_t;
typedef __bf16 bf16x8 __attribute__((ext_vector_type(8)));
typedef float  f32x4  __attribute__((ext_vector_type(4)));

static_assert(sizeof(bf16x8) == 16, "bf16x8 must be 16B");

__device__ __forceinline__ f32x4 mfma_16x16x32_bf16(bf16x8 a, bf16x8 b, f32x4 c) {
    return __builtin_amdgcn_mfma_f32_16x16x32_bf16(a, b, c, 0, 0, 0);
}

// Split 8 consecutive f32 (two float4 loads) into hi/lo bf16x8 fragments.
__device__ __forceinline__ void split8(const float* __restrict__ src,
                                       bf16x8& hi, bf16x8& lo) {
    const f32x4 a = *(const f32x4*)src;
    const f32x4 b = *(const f32x4*)(src + 4);
    #pragma unroll
    for (int j = 0; j < 4; ++j) {
        const bf16_t h0 = (bf16_t)a[j];
        hi[j] = h0;  lo[j] = (bf16_t)(a[j] - (float)h0);
        const bf16_t h1 = (bf16_t)b[j];
        hi[4 + j] = h1;  lo[4 + j] = (bf16_t)(b[j] - (float)h1);
    }
}

// Counter barrier, fresh slot per use (no reset races). Validated on HW in R0:
// release fence -> atomicAdd(AGENT) -> acquire spin -> fence.
__device__ __forceinline__ void ctr_barrier(unsigned int* slot, unsigned int target) {
    __threadfence();                  // release: prior writes visible device-wide
    __syncthreads();
    if (threadIdx.x == 0) {
        __hip_atomic_fetch_add(slot, 1u, __ATOMIC_RELEASE, __HIP_MEMORY_SCOPE_AGENT);
        int guard = 0;
        while (__hip_atomic_load(slot, __ATOMIC_ACQUIRE, __HIP_MEMORY_SCOPE_AGENT) < target) {
            __builtin_amdgcn_s_sleep(2);
            if (++guard > (1 << 22)) break;   // fail visibly, don't hang the queue
        }
    }
    __syncthreads();
    __threadfence();                  // acquire: discard stale cached h lines
}

// Persistent bidirectional LSTM, FP32 I/O, split-bf16 MFMA (acc = Ahi*Bhi +
// Ahi*Blo + Alo*Bhi in f32), custom device barrier. grid = 256 x 256; blocks
// 0..127 forward, 128..255 backward. Each WG owns CHUNK=8 h-columns -> 32
// gate rows r = jj*4 + gate so the MFMA C layout (col=lane&15, row=quad*4+reg)
// puts f,i,g,o of one (b,col) in regs 0..3 of one lane. [U;W] hi/lo fragments
// live in VGPRs for all 512 steps.
__global__ __launch_bounds__(256, 1)
void lstm_persistent(const float* __restrict__ x,
                     const float* __restrict__ h0,
                     const float* __restrict__ c0,
                     const float* __restrict__ Ufw, const float* __restrict__ Ufb,
                     const float* __restrict__ Wfw, const float* __restrict__ Wfb,
                     const float* __restrict__ Ubw, const float* __restrict__ Ubb,
                     const float* __restrict__ Wbw, const float* __restrict__ Wbb,
                     bf16_t* __restrict__ xhi,    // [B][T][E] bf16 plane
                     bf16_t* __restrict__ xlo,    // [B][T][E] bf16 plane
                     bf16_t* __restrict__ hbuf,   // [parity2][dir2][plane2][B][H]
                     float*  __restrict__ out,    // [B][T][H] f32 + [2][B][H] tail
                     unsigned int* __restrict__ ctr) // [1 + 2*TT]
{
    __shared__ f32x4 red[4][8][64];   // [wave][tile][lane] partials, 32 KiB

    const int wg   = blockIdx.x;
    const int dir  = wg >> 7;
    const int cb   = (wg & 127) * CHUNK;
    const int tid  = threadIdx.x;
    const int wave = tid >> 6;
    const int lane = tid & 63;
    const int l16  = lane & 15;
    const int quad = lane >> 4;

    const float* Uw = dir ? Ubw : Ufw;
    const float* Ww = dir ? Wbw : Wfw;
    const float* Ub = dir ? Ubb : Ufb;
    const float* Wb = dir ? Wbb : Wfb;

    // ================= pre-phase (before FULL-GRID barrier) =================
    const int gid = wg * 256 + tid;          // 0 .. 65535
    // (A) split x into hi/lo planes: 2,097,152 groups of 8 elements
    {
        const int NG = BB * TT * EE / 8;
        for (int g = gid; g < NG; g += NWG * 256) {
            bf16x8 hi, lo;
            split8(x + (size_t)g * 8, hi, lo);
            ((bf16x8*)xhi)[g] = hi;
            ((bf16x8*)xlo)[g] = lo;
        }
    }
    // (B) zero out[0 : B*T*H)
    {
        const int NZ = BB * TT * HH / 4;
        const f32x4 z = {0.f, 0.f, 0.f, 0.f};
        for (int g = gid; g < NZ; g += NWG * 256) ((f32x4*)out)[g] = z;
    }
    // (C) tail passthrough: out[BTH : BTH+BH) = h0, then c0
    {
        float* tail = out + (size_t)BB * TT * HH;
        const int NT4 = BB * HH / 4;
        for (int g = gid; g < NT4; g += NWG * 256)
            ((f32x4*)tail)[g] = ((const f32x4*)h0)[g];
        for (int g = gid; g < NT4; g += NWG * 256)
            ((f32x4*)(tail + BB * HH))[g] = ((const f32x4*)c0)[g];
    }
    // (D) stage split h0 chunk (own columns) into parity-1 planes
    {
        bf16_t* p1hi = hbuf + ((size_t)((1 * 2 + dir) * 2) + 0) * (BB * HH);
        bf16_t* p1lo = hbuf + ((size_t)((1 * 2 + dir) * 2) + 1) * (BB * HH);
        for (int i = tid; i < BB * CHUNK; i += 256) {
            const int b = i >> 3, col = cb + (i & 7);
            const float v = h0[b * HH + col];
            const bf16_t vh = (bf16_t)v;
            p1hi[b * HH + col] = vh;
            p1lo[b * HH + col] = (bf16_t)(v - (float)vh);
        }
    }

    // ---- preload [U;W] hi/lo fragments (A operand) into registers ----
    // A[m][k]: m = lane&15 (row in 16-row mt tile), k = quad*8+j in the 32-wide
    // window at ws0 = wave*KSLICE + ki*32. Windows never straddle E.
    bf16x8 whi[2][NKI], wlo[2][NKI];
    #pragma unroll
    for (int mt = 0; mt < 2; ++mt) {
        const int r    = mt * 16 + l16;                  // local row 0..31
        const int grow = (r & 3) * HH + (cb + (r >> 2)); // gate*H + hcol
        const float* urow = Uw + (size_t)grow * EE;
        const float* wrow = Ww + (size_t)grow * HH;
        #pragma unroll
        for (int ki = 0; ki < NKI; ++ki) {
            const int ws0 = wave * KSLICE + ki * 32;
            const float* src = (ws0 < EE ? urow + ws0 : wrow + (ws0 - EE)) + quad * 8;
            split8(src, whi[mt][ki], wlo[mt][ki]);
        }
    }

    // Epilogue ownership: wave w finalizes nt == w -> batch b = wave*16 + l16,
    // h-col = cb + mt*4 + quad, gates f,i,g,o in regs 0..3.
    const int bown = wave * 16 + l16;
    float biasv[2][4];
    float cst[2];
    #pragma unroll
    for (int mt = 0; mt < 2; ++mt) {
        const int hcol = cb + mt * 4 + quad;
        #pragma unroll
        for (int g = 0; g < 4; ++g)
            biasv[mt][g] = Ub[g * HH + hcol] + Wb[g * HH + hcol];
        cst[mt] = c0[bown * HH + hcol];
    }

    // FULL-GRID barrier: x planes / out zero / tail / h0 staging visible to BOTH
    // directions (a per-dir barrier here was the R3-design race).
    ctr_barrier(ctr + 0, NWG);

    unsigned int* stepctr = ctr + 1 + dir * TT;
    const f32x4 vzero = {0.f, 0.f, 0.f, 0.f};

    for (int t = 0; t < TT; ++t) {
        const int tx = dir ? (TT - 1 - t) : t;
        const int rp = (t + 1) & 1;          // read parity
        const bf16_t* hphi = hbuf + ((size_t)((rp * 2 + dir) * 2) + 0) * (BB * HH);
        const bf16_t* hplo = hbuf + ((size_t)((rp * 2 + dir) * 2) + 1) * (BB * HH);

        f32x4 acc[2][4];
        #pragma unroll
        for (int mt = 0; mt < 2; ++mt)
            #pragma unroll
            for (int nt = 0; nt < 4; ++nt) acc[mt][nt] = vzero;

        const bf16_t *xrh[4], *xrl[4], *hrh[4], *hrl[4];
        #pragma unroll
        for (int nt = 0; nt < 4; ++nt) {
            const int b = nt * 16 + l16;     // B-operand: n = lane&15
            const size_t xoff = ((size_t)b * TT + tx) * EE;
            xrh[nt] = xhi + xoff;  xrl[nt] = xlo + xoff;
            hrh[nt] = hphi + (size_t)b * HH;
            hrl[nt] = hplo + (size_t)b * HH;
        }

        const int ws0base = wave * KSLICE;
        bf16x8 bhc[4], blc[4], bhn[4], bln[4];
        {
            const int ws0 = ws0base;
            const int off = (ws0 < EE ? ws0 : ws0 - EE) + quad * 8;
            const bool fromx = ws0 < EE;
            #pragma unroll
            for (int nt = 0; nt < 4; ++nt) {
                bhc[nt] = *(const bf16x8*)((fromx ? xrh[nt] : hrh[nt]) + off);
                blc[nt] = *(const bf16x8*)((fromx ? xrl[nt] : hrl[nt]) + off);
            }
        }
        #pragma unroll
        for (int ki = 0; ki < NKI; ++ki) {
            if (ki + 1 < NKI) {
                const int ws0 = ws0base + (ki + 1) * 32;
                const int off = (ws0 < EE ? ws0 : ws0 - EE) + quad * 8;
                const bool fromx = ws0 < EE;
                #pragma unroll
                for (int nt = 0; nt < 4; ++nt) {
                    bhn[nt] = *(const bf16x8*)((fromx ? xrh[nt] : hrh[nt]) + off);
                    bln[nt] = *(const bf16x8*)((fromx ? xrl[nt] : hrl[nt]) + off);
                }
            }
            #pragma unroll
            for (int mt = 0; mt < 2; ++mt)
                #pragma unroll
                for (int nt = 0; nt < 4; ++nt) {
                    acc[mt][nt] = mfma_16x16x32_bf16(whi[mt][ki], bhc[nt], acc[mt][nt]);
                    acc[mt][nt] = mfma_16x16x32_bf16(whi[mt][ki], blc[nt], acc[mt][nt]);
                    acc[mt][nt] = mfma_16x16x32_bf16(wlo[mt][ki], bhc[nt], acc[mt][nt]);
                }
            #pragma unroll
            for (int nt = 0; nt < 4; ++nt) { bhc[nt] = bhn[nt]; blc[nt] = bln[nt]; }
        }

        // K-reduction across waves through LDS.
        #pragma unroll
        for (int mt = 0; mt < 2; ++mt)
            #pragma unroll
            for (int nt = 0; nt < 4; ++nt)
                red[wave][mt * 4 + nt][lane] = acc[mt][nt];
        __syncthreads();

        const int wp = t & 1;                // write parity
        bf16_t* hnhi = hbuf + ((size_t)((wp * 2 + dir) * 2) + 0) * (BB * HH);
        bf16_t* hnlo = hbuf + ((size_t)((wp * 2 + dir) * 2) + 1) * (BB * HH);
        #pragma unroll
        for (int mt = 0; mt < 2; ++mt) {
            const int tI = mt * 4 + wave;    // this wave finalizes nt == wave
            f32x4 s = red[0][tI][lane];
            #pragma unroll
            for (int w2 = 1; w2 < 4; ++w2) s += red[w2][tI][lane];
            const float fg = s[0] + biasv[mt][0];
            const float ig = s[1] + biasv[mt][1];
            const float gg = s[2] + biasv[mt][2];
            const float og = s[3] + biasv[mt][3];   // o gate used RAW (ref quirk)
            const float sf = 1.f / (1.f + __expf(-fg));
            const float si = 1.f / (1.f + __expf(-ig));
            float cn = cst[mt] * sf + si * tanhf(gg);
            cn = fminf(600.f, fmaxf(-600.f, cn));   // inert when correct
            cst[mt] = cn;
            float hv = og * tanhf(cn);
            hv = fminf(448.f, fmaxf(-448.f, hv));   // inert when correct
            const int hcol = cb + mt * 4 + quad;
            const bf16_t vh = (bf16_t)hv;
            hnhi[(size_t)bown * HH + hcol] = vh;
            hnlo[(size_t)bown * HH + hcol] = (bf16_t)(hv - (float)vh);
            atomicAdd(&out[((size_t)bown * TT + tx) * HH + hcol], hv);
        }
        // publishes hnext; its two __syncthreads also separate red[] epochs
        ctr_barrier(stepctr + t, NWGD);
    }
}

// Diagnostic sentinel: fills out with a constant so failures are attributable.
__global__ void sentinel_kernel(float* __restrict__ out, float v, size_t n)
{
    const size_t i = (size_t)blockIdx.x * blockDim.x + threadIdx.x;
    if (i < n) out[i] = v;
}

extern "C" void kernel_launch(void* const* d_in, const int* in_sizes, int n_in,
                              void* d_out, int out_size, void* d_ws, size_t ws_size,
                              hipStream_t stream)
{
    const float* x   = (const float*)d_in[0];
    const float* h0  = (const float*)d_in[1];
    const float* c0  = (const float*)d_in[2];
    const float* Ufw = (const float*)d_in[3];
    const float* Ufb = (const float*)d_in[4];
    const float* Wfw = (const float*)d_in[5];
    const float* Wfb = (const float*)d_in[6];
    const float* Ubw = (const float*)d_in[7];
    const float* Ubb = (const float*)d_in[8];
    const float* Wbw = (const float*)d_in[9];
    const float* Wbb = (const float*)d_in[10];

    const size_t n_out = (size_t)out_size;

    // ws layout: [ctr 8KB][xhi 32MB][xlo 32MB][hbuf 2MB]
    const size_t CTRB = 8192;
    const size_t XPB  = (size_t)BB * TT * EE * sizeof(bf16_t);        // 32 MiB
    const size_t HBUF = (size_t)2 * 2 * 2 * BB * HH * sizeof(bf16_t); // 2 MiB
    if (ws_size < CTRB + 2 * XPB + HBUF) {
        hipLaunchKernelGGL(sentinel_kernel, dim3((unsigned)((n_out + 255) / 256)),
                           dim3(256), 0, stream, (float*)d_out, 1000.0f, n_out);
        return;
    }

    uint8_t* ws = (uint8_t*)d_ws;
    unsigned int* ctr = (unsigned int*)ws;
    bf16_t* xhi  = (bf16_t*)(ws + CTRB);
    bf16_t* xlo  = (bf16_t*)(ws + CTRB + XPB);
    bf16_t* hbuf = (bf16_t*)(ws + CTRB + 2 * XPB);
    float*  out  = (float*)d_out;

    hipMemsetAsync(ctr, 0, CTRB, stream);

    hipLaunchKernelGGL(lstm_persistent, dim3(NWG), dim3(256), 0, stream,
                       x, h0, c0, Ufw, Ufb, Wfw, Wfb, Ubw, Ubb, Wbw, Wbb,
                       xhi, xlo, hbuf, out, ctr);
}

// Round 5
// 13097.089 us; speedup vs baseline: 2.8890x; 2.8890x over previous
//
#include <hip/hip_runtime.h>
#include <hip/hip_bf16.h>
#include <stdint.h>

// Problem dims
#define BB 64
#define TT 512
#define EE 512
#define HH 1024
#define KTOT 1536          // E + H
#define CHUNK 8            // h-columns per workgroup (128 WGs per direction)
#define NKI 12             // K windows of 32 per wave (4 waves x 12 x 32 = 1536)
#define NWGD 128           // workgroups per direction
#define NWG  256           // total workgroups

typedef __bf16 bf16_t;
typedef __bf16 bf16x8 __attribute__((ext_vector_type(8)));
typedef float  f32x4  __attribute__((ext_vector_type(4)));

static_assert(sizeof(bf16x8) == 16, "bf16x8 must be 16B");

__device__ __forceinline__ f32x4 mfma_16x16x32_bf16(bf16x8 a, bf16x8 b, f32x4 c) {
    return __builtin_amdgcn_mfma_f32_16x16x32_bf16(a, b, c, 0, 0, 0);
}

// Split 8 consecutive f32 (two float4 loads) into hi/lo bf16x8 fragments.
__device__ __forceinline__ void split8(const float* __restrict__ src,
                                       bf16x8& hi, bf16x8& lo) {
    const f32x4 a = *(const f32x4*)src;
    const f32x4 b = *(const f32x4*)(src + 4);
    #pragma unroll
    for (int j = 0; j < 4; ++j) {
        const bf16_t h0 = (bf16_t)a[j];
        hi[j] = h0;  lo[j] = (bf16_t)(a[j] - (float)h0);
        const bf16_t h1 = (bf16_t)b[j];
        hi[4 + j] = h1;  lo[4 + j] = (bf16_t)(b[j] - (float)h1);
    }
}

// FENCE-FREE counter barrier (fresh slot per use). h traffic is sc1-coherent
// (relaxed agent atomics), so no cache maintenance is needed: __syncthreads'
// implicit s_waitcnt vmcnt(0) drains the h stores to the coherence point.
__device__ __forceinline__ void ctr_barrier(unsigned int* slot, unsigned int target) {
    __syncthreads();                  // drains each wave's vmem (incl. sc1 h stores)
    if (threadIdx.x == 0) {
        __hip_atomic_fetch_add(slot, 1u, __ATOMIC_RELAXED, __HIP_MEMORY_SCOPE_AGENT);
        int guard = 0;
        while (__hip_atomic_load(slot, __ATOMIC_RELAXED, __HIP_MEMORY_SCOPE_AGENT) < target) {
            __builtin_amdgcn_s_sleep(2);
            if (++guard > (1 << 22)) break;   // fail visibly, don't hang the queue
        }
    }
    __syncthreads();
}

// B-operand window load: x windows from plain-cached bf16 planes; h windows
// from the packed u32 (hi,lo) coherent buffer via relaxed agent u64 atomics.
// ws0 is wave-uniform and unrolled => branch resolves at compile time.
__device__ __forceinline__ void load_b(int ws0,
                                       const bf16_t* __restrict__ xh,
                                       const bf16_t* __restrict__ xl,
                                       const unsigned int* __restrict__ hrow32,
                                       int quad, bf16x8& bh, bf16x8& bl) {
    if (ws0 < EE) {
        bh = *(const bf16x8*)(xh + ws0 + quad * 8);
        bl = *(const bf16x8*)(xl + ws0 + quad * 8);
    } else {
        const unsigned long long* p =
            (const unsigned long long*)(hrow32 + (ws0 - EE) + quad * 8);
        #pragma unroll
        for (int j = 0; j < 4; ++j) {
            unsigned long long v = __hip_atomic_load(p + j, __ATOMIC_RELAXED,
                                                     __HIP_MEMORY_SCOPE_AGENT);
            bh[2 * j]     = __builtin_bit_cast(bf16_t, (unsigned short)(v & 0xffffull));
            bl[2 * j]     = __builtin_bit_cast(bf16_t, (unsigned short)((v >> 16) & 0xffffull));
            bh[2 * j + 1] = __builtin_bit_cast(bf16_t, (unsigned short)((v >> 32) & 0xffffull));
            bl[2 * j + 1] = __builtin_bit_cast(bf16_t, (unsigned short)((v >> 48) & 0xffffull));
        }
    }
}

// Persistent bidirectional LSTM, FP32 I/O, split-bf16 MFMA (acc = Ahi*Bhi +
// Ahi*Blo + Alo*Bhi in f32). grid = 256 x 256; blocks 0..127 fwd, 128..255 bwd.
// Each WG owns CHUNK=8 h-columns -> 32 gate rows r = jj*4 + gate so the MFMA C
// layout (col=lane&15, row=quad*4+reg) puts f,i,g,o of one (b,col) in regs
// 0..3 of one lane. [U;W] hi/lo fragments live in VGPRs for all 512 steps.
// K windows interleaved: ws0 = (ki*4+wave)*32 -> every wave gets 4 x-windows
// (L2-warm) + 8 h-windows (IC-coherent), balancing latency exposure.
__global__ __launch_bounds__(256, 1)
void lstm_persistent(const float* __restrict__ x,
                     const float* __restrict__ h0,
                     const float* __restrict__ c0,
                     const float* __restrict__ Ufw, const float* __restrict__ Ufb,
                     const float* __restrict__ Wfw, const float* __restrict__ Wfb,
                     const float* __restrict__ Ubw, const float* __restrict__ Ubb,
                     const float* __restrict__ Wbw, const float* __restrict__ Wbb,
                     bf16_t* __restrict__ xhi,    // [B][T][E] bf16 plane
                     bf16_t* __restrict__ xlo,    // [B][T][E] bf16 plane
                     unsigned int* __restrict__ hbuf, // [parity2][dir2][B][H] u32(hi,lo)
                     float*  __restrict__ out,    // [B][T][H] f32 + [2][B][H] tail
                     unsigned int* __restrict__ ctr) // [1 + 2*TT]
{
    __shared__ f32x4 red[4][8][64];   // [wave][tile][lane] partials, 32 KiB

    const int wg   = blockIdx.x;
    const int dir  = wg >> 7;
    const int cb   = (wg & 127) * CHUNK;
    const int tid  = threadIdx.x;
    const int wave = tid >> 6;
    const int lane = tid & 63;
    const int l16  = lane & 15;
    const int quad = lane >> 4;

    const float* Uw = dir ? Ubw : Ufw;
    const float* Ww = dir ? Wbw : Wfw;
    const float* Ub = dir ? Ubb : Ufb;
    const float* Wb = dir ? Wbb : Wfb;

    // ================= pre-phase (before the one-time fence) =================
    const int gid = wg * 256 + tid;          // 0 .. 65535
    // (A) split x into hi/lo planes (plain stores; flushed by the one fence)
    {
        const int NG = BB * TT * EE / 8;
        for (int g = gid; g < NG; g += NWG * 256) {
            bf16x8 hi, lo;
            split8(x + (size_t)g * 8, hi, lo);
            ((bf16x8*)xhi)[g] = hi;
            ((bf16x8*)xlo)[g] = lo;
        }
    }
    // (B) zero out[0 : B*T*H)  (atomicAdds later bypass L2 -> must be flushed)
    {
        const int NZ = BB * TT * HH / 4;
        const f32x4 z = {0.f, 0.f, 0.f, 0.f};
        for (int g = gid; g < NZ; g += NWG * 256) ((f32x4*)out)[g] = z;
    }
    // (C) tail passthrough: out[BTH : BTH+BH) = h0, then c0
    {
        float* tail = out + (size_t)BB * TT * HH;
        const int NT4 = BB * HH / 4;
        for (int g = gid; g < NT4; g += NWG * 256)
            ((f32x4*)tail)[g] = ((const f32x4*)h0)[g];
        for (int g = gid; g < NT4; g += NWG * 256)
            ((f32x4*)(tail + BB * HH))[g] = ((const f32x4*)c0)[g];
    }
    // (D) stage packed split h0 (own columns) into parity-1 buffer (sc1 stores)
    {
        unsigned int* p1 = hbuf + ((size_t)(1 * 2 + dir)) * (BB * HH);
        for (int i = tid; i < BB * CHUNK; i += 256) {
            const int b = i >> 3, col = cb + (i & 7);
            const float v = h0[b * HH + col];
            const bf16_t vh = (bf16_t)v;
            const bf16_t vl = (bf16_t)(v - (float)vh);
            const unsigned int pk =
                (unsigned int)__builtin_bit_cast(unsigned short, vh) |
                ((unsigned int)__builtin_bit_cast(unsigned short, vl) << 16);
            __hip_atomic_store(&p1[b * HH + col], pk, __ATOMIC_RELAXED,
                               __HIP_MEMORY_SCOPE_AGENT);
        }
    }

    // ---- preload [U;W] hi/lo fragments (A operand) into registers ----
    bf16x8 whi[2][NKI], wlo[2][NKI];
    #pragma unroll
    for (int mt = 0; mt < 2; ++mt) {
        const int r    = mt * 16 + l16;                  // local row 0..31
        const int grow = (r & 3) * HH + (cb + (r >> 2)); // gate*H + hcol
        const float* urow = Uw + (size_t)grow * EE;
        const float* wrow = Ww + (size_t)grow * HH;
        #pragma unroll
        for (int ki = 0; ki < NKI; ++ki) {
            const int ws0 = (ki * 4 + wave) * 32;        // interleaved mapping
            const float* src = (ws0 < EE ? urow + ws0 : wrow + (ws0 - EE)) + quad * 8;
            split8(src, whi[mt][ki], wlo[mt][ki]);
        }
    }

    // Epilogue ownership: wave w finalizes nt == w -> batch b = wave*16 + l16,
    // h-col = cb + mt*4 + quad, gates f,i,g,o in regs 0..3.
    const int bown = wave * 16 + l16;
    float biasv[2][4];
    float cst[2];
    #pragma unroll
    for (int mt = 0; mt < 2; ++mt) {
        const int hcol = cb + mt * 4 + quad;
        #pragma unroll
        for (int g = 0; g < 4; ++g)
            biasv[mt][g] = Ub[g * HH + hcol] + Wb[g * HH + hcol];
        cst[mt] = c0[bown * HH + hcol];
    }

    // ONE-TIME fence: flush pre-phase plain stores (x planes, out zeros, tail)
    // to the coherence point, then full-grid barrier.
    __threadfence();
    ctr_barrier(ctr + 0, NWG);

    unsigned int* stepctr = ctr + 1 + dir * TT;
    const f32x4 vzero = {0.f, 0.f, 0.f, 0.f};

    for (int t = 0; t < TT; ++t) {
        const int tx = dir ? (TT - 1 - t) : t;
        const int rp = (t + 1) & 1;          // read parity
        const unsigned int* hb32 = hbuf + ((size_t)(rp * 2 + dir)) * (BB * HH);

        f32x4 acc[2][4];
        #pragma unroll
        for (int mt = 0; mt < 2; ++mt)
            #pragma unroll
            for (int nt = 0; nt < 4; ++nt) acc[mt][nt] = vzero;

        const bf16_t *xrh[4], *xrl[4];
        const unsigned int* hr32[4];
        #pragma unroll
        for (int nt = 0; nt < 4; ++nt) {
            const int b = nt * 16 + l16;     // B-operand: n = lane&15
            const size_t xoff = ((size_t)b * TT + tx) * EE;
            xrh[nt] = xhi + xoff;  xrl[nt] = xlo + xoff;
            hr32[nt] = hb32 + (size_t)b * HH;
        }

        bf16x8 bhc[4], blc[4], bhn[4], bln[4];
        {
            const int ws0 = wave * 32;       // ki = 0
            #pragma unroll
            for (int nt = 0; nt < 4; ++nt)
                load_b(ws0, xrh[nt], xrl[nt], hr32[nt], quad, bhc[nt], blc[nt]);
        }
        #pragma unroll
        for (int ki = 0; ki < NKI; ++ki) {
            if (ki + 1 < NKI) {
                const int ws0 = ((ki + 1) * 4 + wave) * 32;
                #pragma unroll
                for (int nt = 0; nt < 4; ++nt)
                    load_b(ws0, xrh[nt], xrl[nt], hr32[nt], quad, bhn[nt], bln[nt]);
            }
            #pragma unroll
            for (int mt = 0; mt < 2; ++mt)
                #pragma unroll
                for (int nt = 0; nt < 4; ++nt) {
                    acc[mt][nt] = mfma_16x16x32_bf16(whi[mt][ki], bhc[nt], acc[mt][nt]);
                    acc[mt][nt] = mfma_16x16x32_bf16(whi[mt][ki], blc[nt], acc[mt][nt]);
                    acc[mt][nt] = mfma_16x16x32_bf16(wlo[mt][ki], bhc[nt], acc[mt][nt]);
                }
            #pragma unroll
            for (int nt = 0; nt < 4; ++nt) { bhc[nt] = bhn[nt]; blc[nt] = bln[nt]; }
        }

        // K-reduction across waves through LDS.
        #pragma unroll
        for (int mt = 0; mt < 2; ++mt)
            #pragma unroll
            for (int nt = 0; nt < 4; ++nt)
                red[wave][mt * 4 + nt][lane] = acc[mt][nt];
        __syncthreads();

        const int wp = t & 1;                // write parity
        unsigned int* hn32 = hbuf + ((size_t)(wp * 2 + dir)) * (BB * HH);
        #pragma unroll
        for (int mt = 0; mt < 2; ++mt) {
            const int tI = mt * 4 + wave;    // this wave finalizes nt == wave
            f32x4 s = red[0][tI][lane];
            #pragma unroll
            for (int w2 = 1; w2 < 4; ++w2) s += red[w2][tI][lane];
            const float fg = s[0] + biasv[mt][0];
            const float ig = s[1] + biasv[mt][1];
            const float gg = s[2] + biasv[mt][2];
            const float og = s[3] + biasv[mt][3];   // o gate used RAW (ref quirk)
            const float sf = 1.f / (1.f + __expf(-fg));
            const float si = 1.f / (1.f + __expf(-ig));
            float cn = cst[mt] * sf + si * tanhf(gg);
            cn = fminf(600.f, fmaxf(-600.f, cn));   // inert when correct
            cst[mt] = cn;
            float hv = og * tanhf(cn);
            hv = fminf(448.f, fmaxf(-448.f, hv));   // inert when correct
            const int hcol = cb + mt * 4 + quad;
            const bf16_t vh = (bf16_t)hv;
            const bf16_t vl = (bf16_t)(hv - (float)vh);
            const unsigned int pk =
                (unsigned int)__builtin_bit_cast(unsigned short, vh) |
                ((unsigned int)__builtin_bit_cast(unsigned short, vl) << 16);
            __hip_atomic_store(&hn32[(size_t)bown * HH + hcol], pk,
                               __ATOMIC_RELAXED, __HIP_MEMORY_SCOPE_AGENT);
            atomicAdd(&out[((size_t)bown * TT + tx) * HH + hcol], hv);
        }
        if (t + 1 < TT)
            ctr_barrier(stepctr + t, NWGD);  // publishes hnext; separates red[] epochs
    }
}

// Diagnostic sentinel: fills out with a constant so failures are attributable.
__global__ void sentinel_kernel(float* __restrict__ out, float v, size_t n)
{
    const size_t i = (size_t)blockIdx.x * blockDim.x + threadIdx.x;
    if (i < n) out[i] = v;
}

extern "C" void kernel_launch(void* const* d_in, const int* in_sizes, int n_in,
                              void* d_out, int out_size, void* d_ws, size_t ws_size,
                              hipStream_t stream)
{
    const float* x   = (const float*)d_in[0];
    const float* h0  = (const float*)d_in[1];
    const float* c0  = (const float*)d_in[2];
    const float* Ufw = (const float*)d_in[3];
    const float* Ufb = (const float*)d_in[4];
    const float* Wfw = (const float*)d_in[5];
    const float* Wfb = (const float*)d_in[6];
    const float* Ubw = (const float*)d_in[7];
    const float* Ubb = (const float*)d_in[8];
    const float* Wbw = (const float*)d_in[9];
    const float* Wbb = (const float*)d_in[10];

    const size_t n_out = (size_t)out_size;

    // ws layout: [ctr 8KB][xhi 32MB][xlo 32MB][hbuf 2MB u32-packed]
    const size_t CTRB = 8192;
    const size_t XPB  = (size_t)BB * TT * EE * sizeof(bf16_t);        // 32 MiB
    const size_t HBUF = (size_t)2 * 2 * BB * HH * sizeof(unsigned int); // 2 MiB
    if (ws_size < CTRB + 2 * XPB + HBUF) {
        hipLaunchKernelGGL(sentinel_kernel, dim3((unsigned)((n_out + 255) / 256)),
                           dim3(256), 0, stream, (float*)d_out, 1000.0f, n_out);
        return;
    }

    uint8_t* ws = (uint8_t*)d_ws;
    unsigned int* ctr = (unsigned int*)ws;
    bf16_t* xhi  = (bf16_t*)(ws + CTRB);
    bf16_t* xlo  = (bf16_t*)(ws + CTRB + XPB);
    unsigned int* hbuf = (unsigned int*)(ws + CTRB + 2 * XPB);
    float*  out  = (float*)d_out;

    hipMemsetAsync(ctr, 0, CTRB, stream);

    hipLaunchKernelGGL(lstm_persistent, dim3(NWG), dim3(256), 0, stream,
                       x, h0, c0, Ufw, Ufb, Wfw, Wfb, Ubw, Ubb, Wbw, Wbb,
                       xhi, xlo, hbuf, out, ctr);
}